// Round 1
// baseline (163.235 us; speedup 1.0000x reference)
//
#include <hip/hip_runtime.h>
#include <stdint.h>

// out[65536,64] = xa[65536,256] @ wa[256,64] + xb[65536,256] @ wb[256,64]
// = tall-skinny GEMM M=65536, N=64, K=512. Memory-bound (151 MB @ ~6.3 TB/s ~ 24us).
// bf16 MFMA path: compute ~2us, error ~1e-2 << 0.127 threshold.

#define BATCH     65536
#define KH        256
#define NOUT      64
#define WT_SHORTS (512 * 64)       // 32768 bf16
#define WT_BYTES  (WT_SHORTS * 2)  // 65536 B

typedef __bf16 bf16x8 __attribute__((ext_vector_type(8)));
typedef float  f32x4  __attribute__((ext_vector_type(4)));

// Weight layout in d_ws (and LDS): wt[(k>>3)*512 + col*8 + (k&7)], k in [0,512).
// B-fragment for mfma_16x16x32: lane reads 8 consecutive k of one col -> one
// 16B-aligned ds_read_b128. Lanes 0-15 (cols 0-15) land on word-slots 4*c:
// 2-way bank aliasing only (free per m136).

__global__ void prep_wt_kernel(const float* __restrict__ wa,
                               const float* __restrict__ wb,
                               __bf16* __restrict__ wt) {
    int t = blockIdx.x * 256 + threadIdx.x;  // 0..16383
    int c = t & 63;
    int k = t >> 6;                          // 0..255 (coalesced read along c)
    float va = wa[k * 64 + c];
    float vb = wb[k * 64 + c];
    int k2 = k + 256;
    wt[(k  >> 3) * 512 + c * 8 + (k  & 7)] = (__bf16)va;
    wt[(k2 >> 3) * 512 + c * 8 + (k2 & 7)] = (__bf16)vb;
}

template <bool USE_WS>
__global__ __launch_bounds__(512, 4)
void agg_gemm_kernel(const float* __restrict__ xa,
                     const float* __restrict__ xb,
                     const float* __restrict__ wa,
                     const float* __restrict__ wb,
                     const __bf16* __restrict__ wt,
                     float* __restrict__ out) {
    __shared__ __bf16 wlds[WT_SHORTS];   // 64 KB -> 2 blocks/CU (133KB<160KB w/ pad? exactly 128KB)
    const int t    = threadIdx.x;
    const int lane = t & 63;
    const int wave = t >> 6;

    if (USE_WS) {
        // plain vector copy 64KB global(L2) -> LDS: 8 x 16B per thread
        const f32x4* gsrc = (const f32x4*)wt;
        f32x4*       ldst = (f32x4*)&wlds[0];
        #pragma unroll
        for (int it = 0; it < 8; ++it) {
            ldst[it * 512 + t] = gsrc[it * 512 + t];
        }
    } else {
        // fallback: transpose+convert directly from wa/wb (one-time per block)
        int c  = t & 63;
        int kw = t >> 6;  // 0..7
        #pragma unroll
        for (int i = 0; i < 32; ++i) {
            int k  = kw * 32 + i;  // 0..255
            int k2 = k + 256;
            wlds[(k  >> 3) * 512 + c * 8 + (k  & 7)] = (__bf16)wa[k * 64 + c];
            wlds[(k2 >> 3) * 512 + c * 8 + (k2 & 7)] = (__bf16)wb[k * 64 + c];
        }
    }
    __syncthreads();

    // one 16-row tile per wave; 512 blocks * 8 waves = 4096 tiles = 65536/16
    const int gw   = blockIdx.x * 8 + wave;      // tile id 0..4095
    const int row  = gw * 16 + (lane & 15);      // A row (lane&15)
    const int kgrp = lane >> 4;                  // 0..3
    const int kk   = kgrp * 8;                   // A k-offset within 32-wide step

    const float* pa = xa + (size_t)row * 256 + kk;
    const float* pb = xb + (size_t)row * 256 + kk;

    f32x4 acc0 = {0.f, 0.f, 0.f, 0.f};
    f32x4 acc1 = acc0, acc2 = acc0, acc3 = acc0;

    #pragma unroll
    for (int step = 0; step < 16; ++step) {
        const int k0 = step * 32;
        // steps 0..7 read xa (k 0..255), steps 8..15 read xb (k 256..511)
        const float* px = (step < 8) ? (pa + k0) : (pb + (k0 - 256));
        f32x4 x0 = *(const f32x4*)(px);
        f32x4 x1 = *(const f32x4*)(px + 4);
        bf16x8 af;
        af[0] = (__bf16)x0[0]; af[1] = (__bf16)x0[1];
        af[2] = (__bf16)x0[2]; af[3] = (__bf16)x0[3];
        af[4] = (__bf16)x1[0]; af[5] = (__bf16)x1[1];
        af[6] = (__bf16)x1[2]; af[7] = (__bf16)x1[3];

        // B frags: kb = (k0 + kk)/8 = step*4 + kgrp
        const __bf16* bbase = &wlds[(step * 4 + kgrp) * 512 + (lane & 15) * 8];
        bf16x8 b0 = *(const bf16x8*)(bbase);            // cols  0-15
        bf16x8 b1 = *(const bf16x8*)(bbase + 16 * 8);   // cols 16-31
        bf16x8 b2 = *(const bf16x8*)(bbase + 32 * 8);   // cols 32-47
        bf16x8 b3 = *(const bf16x8*)(bbase + 48 * 8);   // cols 48-63

        acc0 = __builtin_amdgcn_mfma_f32_16x16x32_bf16(af, b0, acc0, 0, 0, 0);
        acc1 = __builtin_amdgcn_mfma_f32_16x16x32_bf16(af, b1, acc1, 0, 0, 0);
        acc2 = __builtin_amdgcn_mfma_f32_16x16x32_bf16(af, b2, acc2, 0, 0, 0);
        acc3 = __builtin_amdgcn_mfma_f32_16x16x32_bf16(af, b3, acc3, 0, 0, 0);
    }

    // C/D layout (m89-verified): col = lane&15, row = (lane>>4)*4 + reg
    const int oc = lane & 15;
    float* po = out + (size_t)(gw * 16 + (lane >> 4) * 4) * 64 + oc;
    #pragma unroll
    for (int r = 0; r < 4; ++r) {
        po[r * 64 +  0] = acc0[r];
        po[r * 64 + 16] = acc1[r];
        po[r * 64 + 32] = acc2[r];
        po[r * 64 + 48] = acc3[r];
    }
}

extern "C" void kernel_launch(void* const* d_in, const int* in_sizes, int n_in,
                              void* d_out, int out_size, void* d_ws, size_t ws_size,
                              hipStream_t stream) {
    const float* xa = (const float*)d_in[0];
    const float* xb = (const float*)d_in[1];
    const float* wa = (const float*)d_in[2];
    const float* wb = (const float*)d_in[3];
    float* out = (float*)d_out;

    if (ws_size >= (size_t)WT_BYTES) {
        __bf16* wt = (__bf16*)d_ws;
        prep_wt_kernel<<<64, 256, 0, stream>>>(wa, wb, wt);
        agg_gemm_kernel<true><<<512, 512, 0, stream>>>(xa, xb, wa, wb, wt, out);
    } else {
        agg_gemm_kernel<false><<<512, 512, 0, stream>>>(xa, xb, wa, wb, nullptr, out);
    }
}

// Round 2
// 159.215 us; speedup vs baseline: 1.0252x; 1.0252x over previous
//
#include <hip/hip_runtime.h>
#include <stdint.h>

// out[65536,64] = xa[65536,256] @ wa[256,64] + xb[65536,256] @ wb[256,64]
// Tall-skinny GEMM M=65536, N=64, K=512 (concat). Memory-bound:
// 134 MB read + 17 MB write @ ~6.3 TB/s => ~24 us floor (less w/ L3 residency).
// R0 was latency-bound (1.6 TB/s): VGPR-limited in-flight loads.
// R1: global_load_lds double-buffered wave-private x staging (deep async
// pipeline, counted vmcnt, no in-loop barriers) + weights in LDS.

#define WT_SHORTS (512 * 64)       // 32768 bf16
#define WT_BYTES  (WT_SHORTS * 2)  // 65536 B

typedef __bf16 bf16x8 __attribute__((ext_vector_type(8)));
typedef float  f32x4  __attribute__((ext_vector_type(4)));

// Weight layout in d_ws/LDS: wt[(k>>3)*512 + col*8 + (k&7)], k in [0,512).
__global__ void prep_wt_kernel(const float* __restrict__ wa,
                               const float* __restrict__ wb,
                               __bf16* __restrict__ wt) {
    int t = blockIdx.x * 256 + threadIdx.x;  // 0..16383
    int c = t & 63;
    int k = t >> 6;                          // 0..255
    float va = wa[k * 64 + c];
    float vb = wb[k * 64 + c];
    int k2 = k + 256;
    wt[(k  >> 3) * 512 + c * 8 + (k  & 7)] = (__bf16)va;
    wt[(k2 >> 3) * 512 + c * 8 + (k2 & 7)] = (__bf16)vb;
}

__device__ __forceinline__ void gload16(const void* g, void* l) {
    __builtin_amdgcn_global_load_lds(
        (const __attribute__((address_space(1))) void*)g,
        (__attribute__((address_space(3))) void*)l, 16, 0, 0);
}

template <bool USE_WS>
__global__ __launch_bounds__(512)
void agg_gemm_kernel(const float* __restrict__ xa,
                     const float* __restrict__ xb,
                     const float* __restrict__ wa,
                     const float* __restrict__ wb,
                     const __bf16* __restrict__ wt,
                     float* __restrict__ out) {
    __shared__ __align__(16) __bf16 wlds[WT_SHORTS];   // 64 KB weights
    // x double-buffer: [buf 2][wave 8][16 rows x 64 f32 = 4KB] = 64 KB
    __shared__ __align__(16) float xlds[2 * 8 * 1024];

    const int t    = threadIdx.x;
    const int lane = t & 63;
    const int wave = t >> 6;

    // ---- one-time: weights -> LDS ----
    if (USE_WS) {
        const f32x4* gsrc = (const f32x4*)wt;
        f32x4*       ldst = (f32x4*)&wlds[0];
        #pragma unroll
        for (int it = 0; it < 8; ++it)
            ldst[it * 512 + t] = gsrc[it * 512 + t];
    } else {
        int c  = t & 63;
        int kw = t >> 6;
        #pragma unroll
        for (int i = 0; i < 32; ++i) {
            int k  = kw * 32 + i;
            int k2 = k + 256;
            wlds[(k  >> 3) * 512 + c * 8 + (k  & 7)] = (__bf16)wa[k * 64 + c];
            wlds[(k2 >> 3) * 512 + c * 8 + (k2 & 7)] = (__bf16)wb[k * 64 + c];
        }
    }
    __syncthreads();   // drains all counters; clean slate for manual vmcnt

    const int gw   = blockIdx.x * 8 + wave;   // tile id 0..4095
    const int tile = gw * 16;                 // first row of this wave's tile
    const int row  = lane & 15;               // A-row / B-col within frag
    const int kgrp = lane >> 4;               // 0..3
    const int sw   = (row & 7) << 4;          // 16B-granule XOR swizzle

    char* xw0 = (char*)&xlds[(0 * 8 + wave) * 1024];
    char* xw1 = (char*)&xlds[(1 * 8 + wave) * 1024];

    // Stage chunk c (64 floats of K per row) into buffer (c&1).
    // DMA writes linearly (base + lane*16); the XOR swizzle is applied to
    // the GLOBAL source address (rule #21: both-sides-or-neither).
    const int r_lo = lane >> 4;          // 0..3
    const int fk4  = (lane & 15) * 4;
    auto stage = [&](int c) {
        const float* srcm = (c < 4) ? xa : xb;
        const int k0 = (c & 3) * 64;
        char* ldsb = (c & 1) ? xw1 : xw0;
        #pragma unroll
        for (int j = 0; j < 4; ++j) {
            int r = j * 4 + r_lo;                    // row 0..15
            int f = fk4 ^ ((r & 7) << 2);            // swizzled float idx
            const float* g = srcm + (size_t)(tile + r) * 256 + k0 + f;
            gload16(g, ldsb + j * 1024);
        }
    };

    stage(0);
    stage(1);

    f32x4 acc0 = {0.f, 0.f, 0.f, 0.f};
    f32x4 acc1 = acc0, acc2 = acc0, acc3 = acc0;

    #pragma unroll
    for (int c = 0; c < 8; ++c) {
        // chunk c's 4 loads are the oldest; chunk c+1's 4 may stay in flight
        if (c < 7) asm volatile("s_waitcnt vmcnt(4)" ::: "memory");
        else       asm volatile("s_waitcnt vmcnt(0)" ::: "memory");

        const char* xbb = (c & 1) ? xw1 : xw0;
        #pragma unroll
        for (int sub = 0; sub < 2; ++sub) {
            const int step = c * 2 + sub;            // 0..15
            const int b0   = row * 256 + sub * 128 + kgrp * 32;
            f32x4 x0 = *(const f32x4*)(xbb + (b0 ^ sw));
            f32x4 x1 = *(const f32x4*)(xbb + ((b0 + 16) ^ sw));
            bf16x8 af;
            af[0] = (__bf16)x0[0]; af[1] = (__bf16)x0[1];
            af[2] = (__bf16)x0[2]; af[3] = (__bf16)x0[3];
            af[4] = (__bf16)x1[0]; af[5] = (__bf16)x1[1];
            af[6] = (__bf16)x1[2]; af[7] = (__bf16)x1[3];

            const __bf16* bbase = &wlds[(step * 4 + kgrp) * 512 + row * 8];
            bf16x8 bf0 = *(const bf16x8*)(bbase);          // cols  0-15
            bf16x8 bf1 = *(const bf16x8*)(bbase + 128);    // cols 16-31
            bf16x8 bf2 = *(const bf16x8*)(bbase + 256);    // cols 32-47
            bf16x8 bf3 = *(const bf16x8*)(bbase + 384);    // cols 48-63

            acc0 = __builtin_amdgcn_mfma_f32_16x16x32_bf16(af, bf0, acc0, 0, 0, 0);
            acc1 = __builtin_amdgcn_mfma_f32_16x16x32_bf16(af, bf1, acc1, 0, 0, 0);
            acc2 = __builtin_amdgcn_mfma_f32_16x16x32_bf16(af, bf2, acc2, 0, 0, 0);
            acc3 = __builtin_amdgcn_mfma_f32_16x16x32_bf16(af, bf3, acc3, 0, 0, 0);
        }

        if (c < 6) {
            // buffer (c&1) is about to be overwritten by chunk c+2's DMA:
            // make sure our ds_reads of it have completed first.
            asm volatile("s_waitcnt lgkmcnt(0)" ::: "memory");
            __builtin_amdgcn_sched_barrier(0);
            stage(c + 2);
        }
    }

    // C/D layout: col = lane&15, out-row = kgrp*4 + reg
    float* po = out + (size_t)(tile + kgrp * 4) * 64 + row;
    #pragma unroll
    for (int r = 0; r < 4; ++r) {
        po[r * 64 +  0] = acc0[r];
        po[r * 64 + 16] = acc1[r];
        po[r * 64 + 32] = acc2[r];
        po[r * 64 + 48] = acc3[r];
    }
}

extern "C" void kernel_launch(void* const* d_in, const int* in_sizes, int n_in,
                              void* d_out, int out_size, void* d_ws, size_t ws_size,
                              hipStream_t stream) {
    const float* xa = (const float*)d_in[0];
    const float* xb = (const float*)d_in[1];
    const float* wa = (const float*)d_in[2];
    const float* wb = (const float*)d_in[3];
    float* out = (float*)d_out;

    if (ws_size >= (size_t)WT_BYTES) {
        __bf16* wt = (__bf16*)d_ws;
        prep_wt_kernel<<<64, 256, 0, stream>>>(wa, wb, wt);
        agg_gemm_kernel<true><<<512, 512, 0, stream>>>(xa, xb, wa, wb, wt, out);
    } else {
        agg_gemm_kernel<false><<<512, 512, 0, stream>>>(xa, xb, wa, wb, nullptr, out);
    }
}